// Round 5
// baseline (117.727 us; speedup 1.0000x reference)
//
#include <hip/hip_runtime.h>
#include <math.h>

#define NN 4096
#define NFEAT 1870
#define KPAD 1920
#define HID 256
#define EMB 16
#define MAXDEG 128

typedef __attribute__((ext_vector_type(8))) _Float16 f16x8;
typedef __attribute__((ext_vector_type(4))) float f32x4;

__device__ __forceinline__ ushort f2h(float f) {
    _Float16 h = (_Float16)f;
    return __builtin_bit_cast(ushort, h);
}

// ---------------------------------------------------------------------------
// x [NN][NFEAT] fp32 -> xf16 [NN][KPAD] f16, zero-padded K. 8 elems/thread.
// ---------------------------------------------------------------------------
__global__ __launch_bounds__(256) void xcv_kernel(
    const float* __restrict__ x, ushort* __restrict__ xf)
{
    const int idx = blockIdx.x * 256 + threadIdx.x;
    const int row = idx / 240;
    const int c0 = (idx % 240) * 8;
    float v[8];
    if (c0 + 8 <= NFEAT) {
#pragma unroll
        for (int j = 0; j < 4; ++j) {
            float2 t = *(const float2*)&x[(size_t)row * NFEAT + c0 + j * 2];
            v[j * 2] = t.x; v[j * 2 + 1] = t.y;
        }
    } else {
#pragma unroll
        for (int j = 0; j < 8; ++j)
            v[j] = (c0 + j < NFEAT) ? x[(size_t)row * NFEAT + c0 + j] : 0.f;
    }
    ushort u[8];
#pragma unroll
    for (int j = 0; j < 8; ++j) u[j] = f2h(v[j]);
    *(int4*)&xf[(size_t)row * KPAD + c0] = *(int4*)u;
}

// ---------------------------------------------------------------------------
// W1 [NFEAT][HID] fp32 -> W1T f16 [HID][KPAD], zero-padded K.
// ---------------------------------------------------------------------------
__global__ __launch_bounds__(256) void conv_w1t_kernel(
    const float* __restrict__ W1, ushort* __restrict__ Wh)
{
    __shared__ float t[64][65];
    const int tid = threadIdx.x;
    const int k0 = blockIdx.x * 64, n0 = blockIdx.y * 64;
    const int kk = tid >> 2, c4 = (tid & 3) * 16;
#pragma unroll
    for (int j = 0; j < 4; ++j) {
        int k = k0 + kk;
        float4 v = make_float4(0.f, 0.f, 0.f, 0.f);
        if (k < NFEAT) v = *(const float4*)&W1[(size_t)k * HID + n0 + c4 + j * 4];
        t[kk][c4 + j * 4 + 0] = v.x; t[kk][c4 + j * 4 + 1] = v.y;
        t[kk][c4 + j * 4 + 2] = v.z; t[kk][c4 + j * 4 + 3] = v.w;
    }
    __syncthreads();
    const int on = tid >> 2, ok4 = (tid & 3) * 16;
#pragma unroll
    for (int j = 0; j < 4; ++j) {
        ushort hh[4];
#pragma unroll
        for (int i = 0; i < 4; ++i)
            hh[i] = f2h(t[ok4 + j * 4 + i][on]);
        size_t o = (size_t)(n0 + on) * KPAD + k0 + ok4 + j * 4;
        *(ushort4*)&Wh[o] = *(ushort4*)hh;
    }
}

// ---------------------------------------------------------------------------
// h1 partials = xf16 @ W1T^T, single-pass f16 MFMA.
// Tile 128x64, 4 waves (2x2), BK=64, split-K x4 (chunk 512, z=3 gets 384).
// Reg-prefetched staging, XOR-swizzled LDS (16B slot ^ row&7).
// ---------------------------------------------------------------------------
__global__ __launch_bounds__(256) void gemm_xw1(
    const ushort* __restrict__ Ag,   // [NN][KPAD]
    const ushort* __restrict__ Bg,   // [HID][KPAD]
    float* __restrict__ Cpart)
{
    __shared__ ushort Ah[128 * 64];
    __shared__ ushort Bh[64 * 64];
    const int tid = threadIdx.x;
    const int lane = tid & 63;
    const int w = tid >> 6;
    const int wr = w >> 1, wc = w & 1;
    const int row0 = blockIdx.x * 128;
    const int col0 = blockIdx.y * 64;
    const int kbeg = blockIdx.z * 512;
    const int kend = min(KPAD, kbeg + 512);
    const int nsteps = (kend - kbeg) >> 6;

    const int fr = lane & 15, fs = lane >> 4;

    const int a_row = tid >> 1;             // 4 slots/thread, 2 thr/row
    const int a_sk0 = (tid & 1) * 4;
    const int b_row = tid >> 2;             // 2 slots/thread, 4 thr/row
    const int b_sk0 = (tid & 3) * 2;

    const size_t a_gbase = (size_t)(row0 + a_row) * KPAD;
    const size_t b_gbase = (size_t)(col0 + b_row) * KPAD;

    int4 ra[4], rb[2];
#define LOADAB(K0)                                                        \
    {                                                                     \
        _Pragma("unroll")                                                 \
        for (int i = 0; i < 4; ++i)                                       \
            ra[i] = *(const int4*)&Ag[a_gbase + (K0) + (a_sk0 + i) * 8];  \
        _Pragma("unroll")                                                 \
        for (int i = 0; i < 2; ++i)                                       \
            rb[i] = *(const int4*)&Bg[b_gbase + (K0) + (b_sk0 + i) * 8];  \
    }

    LOADAB(kbeg);
    f32x4 acc[4][2] = {};

    for (int ks = 0; ks < nsteps; ++ks) {
        __syncthreads();
#pragma unroll
        for (int i = 0; i < 4; ++i)
            *(int4*)&Ah[(a_row * 8 + ((a_sk0 + i) ^ (a_row & 7))) * 8] = ra[i];
#pragma unroll
        for (int i = 0; i < 2; ++i)
            *(int4*)&Bh[(b_row * 8 + ((b_sk0 + i) ^ (b_row & 7))) * 8] = rb[i];
        __syncthreads();
        if (ks + 1 < nsteps) LOADAB(kbeg + (ks + 1) * 64);

        f16x8 af[4][2], bf[2][2];
#pragma unroll
        for (int m = 0; m < 4; ++m) {
            int r = wr * 64 + m * 16 + fr;
#pragma unroll
            for (int kf = 0; kf < 2; ++kf) {
                int sk = kf * 4 + fs;
                af[m][kf] = *(const f16x8*)&Ah[(r * 8 + (sk ^ (r & 7))) * 8];
            }
        }
#pragma unroll
        for (int n = 0; n < 2; ++n) {
            int r = wc * 32 + n * 16 + fr;
#pragma unroll
            for (int kf = 0; kf < 2; ++kf) {
                int sk = kf * 4 + fs;
                bf[n][kf] = *(const f16x8*)&Bh[(r * 8 + (sk ^ (r & 7))) * 8];
            }
        }
#pragma unroll
        for (int m = 0; m < 4; ++m)
#pragma unroll
            for (int n = 0; n < 2; ++n)
#pragma unroll
                for (int kf = 0; kf < 2; ++kf)
                    acc[m][n] = __builtin_amdgcn_mfma_f32_16x16x32_f16(
                        af[m][kf], bf[n][kf], acc[m][n], 0, 0, 0);
    }
    float* Cp = Cpart + (size_t)blockIdx.z * NN * HID;
#pragma unroll
    for (int m = 0; m < 4; ++m)
#pragma unroll
        for (int n = 0; n < 2; ++n)
#pragma unroll
            for (int r = 0; r < 4; ++r) {
                int row = row0 + wr * 64 + m * 16 + fs * 4 + r;
                int col = col0 + wc * 32 + n * 16 + fr;
                Cp[(size_t)row * HID + col] = acc[m][n][r];
            }
}

// ---------------------------------------------------------------------------
// h1 = sum of 4 split-K partials; fused fs1/fn1 (one wave per row).
// ---------------------------------------------------------------------------
__global__ __launch_bounds__(256) void reduce_h1f_kernel(
    const float* __restrict__ part, float* __restrict__ h1,
    const float* __restrict__ a_s, const float* __restrict__ a_n,
    float* __restrict__ fs, float* __restrict__ fn)
{
    const int tid = threadIdx.x, wv = tid >> 6, lane = tid & 63;
    const int row = blockIdx.x * 4 + wv;
    const int d0 = lane * 4;
    const size_t o = (size_t)row * HID + d0;
    float4 s = *(const float4*)&part[o];
#pragma unroll
    for (int ch = 1; ch < 4; ++ch) {
        float4 p = *(const float4*)&part[(size_t)ch * NN * HID + o];
        s.x += p.x; s.y += p.y; s.z += p.z; s.w += p.w;
    }
    *(float4*)&h1[o] = s;
    float4 as4 = *(const float4*)&a_s[d0];
    float4 an4 = *(const float4*)&a_n[d0];
    float ps = s.x * as4.x + s.y * as4.y + s.z * as4.z + s.w * as4.w;
    float pn = s.x * an4.x + s.y * an4.y + s.z * an4.z + s.w * an4.w;
#pragma unroll
    for (int off = 32; off > 0; off >>= 1) {
        ps += __shfl_down(ps, off, 64);
        pn += __shfl_down(pn, off, 64);
    }
    if (lane == 0) { fs[row] = ps; fn[row] = pn; }
}

// ---------------------------------------------------------------------------
// Sparse extraction: ordered neighbor compaction + gathered M. 1 wave/row.
// ---------------------------------------------------------------------------
__global__ __launch_bounds__(256) void extract_kernel(
    const float* __restrict__ adj, const float* __restrict__ Mmat,
    int* __restrict__ nnz, int* __restrict__ gidx, float* __restrict__ Mg)
{
    __shared__ int sidx[4][MAXDEG];
    const int tid = threadIdx.x;
    const int wv = tid >> 6, lane = tid & 63;
    const int row = blockIdx.x * 4 + wv;

    int base = 0;
#pragma unroll 4
    for (int t = 0; t < 16; ++t) {
        int j0 = t * 256 + lane * 4;
        float4 a = *(const float4*)&adj[(size_t)row * NN + j0];
        float av[4] = {a.x, a.y, a.z, a.w};
#pragma unroll
        for (int c = 0; c < 4; ++c) {
            unsigned long long mb = __ballot(av[c] > 0.f);
            if (av[c] > 0.f) {
                int pos = base + (int)__popcll(mb & ((1ull << lane) - 1ull));
                if (pos < MAXDEG) sidx[wv][pos] = j0 + c;
            }
            base += (int)__popcll(mb);
        }
    }
    const int cnt = min(base, MAXDEG);
    if (lane == 0) nnz[row] = cnt;
    for (int s = lane; s < cnt; s += 64) {
        int j = sidx[wv][s];
        gidx[(size_t)row * MAXDEG + s] = j;
        Mg[(size_t)row * MAXDEG + s] = Mmat[(size_t)row * NN + j];
    }
}

// ---------------------------------------------------------------------------
// Layer-1 fused sparse softmax + SpMM: g1[row,:] = elu( softmax_nb @ h1 ).
// One block per row; thread = output dim.
// ---------------------------------------------------------------------------
__global__ __launch_bounds__(256) void spmm1_kernel(
    const int* __restrict__ nnz, const int* __restrict__ gidx,
    const float* __restrict__ Mg,
    const float* __restrict__ fs, const float* __restrict__ fn,
    const float* __restrict__ h1, float* __restrict__ g1)
{
    __shared__ float p_s[MAXDEG];
    __shared__ int j_s[MAXDEG];
    __shared__ float wred[4], wsum[4];
    const int row = blockIdx.x;
    const int tid = threadIdx.x;
    const int lane = tid & 63, wv = tid >> 6;
    const int cnt = nnz[row];
    const float fsi = fs[row];

    float lmax = -3.0e38f;
    for (int s = tid; s < cnt; s += 256) {
        int j = gidx[(size_t)row * MAXDEG + s];
        j_s[s] = j;
        float e = (fsi + fn[j]) * Mg[(size_t)row * MAXDEG + s];
        e = (e > 0.f) ? e : 0.2f * e;
        p_s[s] = e;
        lmax = fmaxf(lmax, e);
    }
#pragma unroll
    for (int off = 32; off > 0; off >>= 1)
        lmax = fmaxf(lmax, __shfl_down(lmax, off, 64));
    if (lane == 0) wred[wv] = lmax;
    __syncthreads();
    const float m = fmaxf(fmaxf(wred[0], wred[1]), fmaxf(wred[2], wred[3]));

    float lsum = 0.f;
    for (int s = tid; s < cnt; s += 256) {
        float p = __expf(p_s[s] - m);
        p_s[s] = p;
        lsum += p;
    }
#pragma unroll
    for (int off = 32; off > 0; off >>= 1)
        lsum += __shfl_down(lsum, off, 64);
    if (lane == 0) wsum[wv] = lsum;
    __syncthreads();
    const float inv = 1.f / (wsum[0] + wsum[1] + wsum[2] + wsum[3]);

    float acc = 0.f;
#pragma unroll 4
    for (int s = 0; s < cnt; ++s)
        acc += p_s[s] * h1[(size_t)j_s[s] * HID + tid];
    float v = acc * inv;
    v = (v > 0.f) ? v : (__expf(v) - 1.f);
    g1[(size_t)row * HID + tid] = v;
}

// ---------------------------------------------------------------------------
// h2 = g1 @ W2 with fused fs2/fn2 epilogue (16-lane shfl reduce).
// ---------------------------------------------------------------------------
__global__ __launch_bounds__(256) void gemm_h2_kernel(
    const float* __restrict__ g1, const float* __restrict__ W2,
    const float* __restrict__ a_s2, const float* __restrict__ a_n2,
    float* __restrict__ h2, float* __restrict__ fs2, float* __restrict__ fn2)
{
    __shared__ float Ws[256][16];
    __shared__ float Gs[16][257];
    const int tid = threadIdx.x;
    const int row0 = blockIdx.x * 16;
#pragma unroll
    for (int i = 0; i < 16; ++i) {
        int idx = tid + i * 256;
        Ws[idx >> 4][idx & 15] = W2[idx];
    }
#pragma unroll
    for (int i = 0; i < 16; ++i) {
        int idx = tid + i * 256;
        Gs[idx >> 8][idx & 255] = g1[(size_t)(row0 + (idx >> 8)) * HID + (idx & 255)];
    }
    __syncthreads();
    const int r = tid >> 4, c = tid & 15;
    float acc = 0.f;
#pragma unroll 8
    for (int k = 0; k < 256; ++k)
        acc += Gs[r][k] * Ws[k][c];
    h2[(size_t)(row0 + r) * EMB + c] = acc;

    float ps = acc * a_s2[c];
    float pn = acc * a_n2[c];
#pragma unroll
    for (int off = 1; off < 16; off <<= 1) {
        ps += __shfl_xor(ps, off, 64);
        pn += __shfl_xor(pn, off, 64);
    }
    if (c == 0) { fs2[row0 + r] = ps; fn2[row0 + r] = pn; }
}

// ---------------------------------------------------------------------------
// Layer-2 fused sparse softmax + PV + ELU + L2-normalize -> z. 1 wave/row.
// ---------------------------------------------------------------------------
__global__ __launch_bounds__(256) void spmm2_kernel(
    const int* __restrict__ nnz, const int* __restrict__ gidx,
    const float* __restrict__ Mg,
    const float* __restrict__ fs, const float* __restrict__ fn,
    const float* __restrict__ h2, float* __restrict__ z)
{
    __shared__ float p_s[4][MAXDEG];
    __shared__ int j_s[4][MAXDEG];
    const int tid = threadIdx.x;
    const int wv = tid >> 6, lane = tid & 63;
    const int row = blockIdx.x * 4 + wv;
    const int cnt = nnz[row];
    const float fsi = fs[row];

    float lmax = -3.0e38f;
    for (int s = lane; s < cnt; s += 64) {
        int j = gidx[(size_t)row * MAXDEG + s];
        j_s[wv][s] = j;
        float e = (fsi + fn[j]) * Mg[(size_t)row * MAXDEG + s];
        e = (e > 0.f) ? e : 0.2f * e;
        p_s[wv][s] = e;
        lmax = fmaxf(lmax, e);
    }
#pragma unroll
    for (int off = 1; off < 64; off <<= 1)
        lmax = fmaxf(lmax, __shfl_xor(lmax, off, 64));

    float lsum = 0.f;
    for (int s = lane; s < cnt; s += 64) {
        float p = __expf(p_s[wv][s] - lmax);
        p_s[wv][s] = p;
        lsum += p;
    }
#pragma unroll
    for (int off = 1; off < 64; off <<= 1)
        lsum += __shfl_xor(lsum, off, 64);
    const float inv = 1.f / lsum;

    const int s0 = lane >> 4, d = lane & 15;
    float acc = 0.f;
    for (int s = s0; s < cnt; s += 4)
        acc += p_s[wv][s] * h2[(size_t)j_s[wv][s] * EMB + d];
    acc += __shfl_xor(acc, 16, 64);
    acc += __shfl_xor(acc, 32, 64);

    float v = acc * inv;
    v = (v > 0.f) ? v : (__expf(v) - 1.f);
    float ss = v * v;
#pragma unroll
    for (int off = 1; off < 16; off <<= 1)
        ss += __shfl_xor(ss, off, 64);
    float zn = v / fmaxf(sqrtf(ss), 1e-12f);
    if (lane < 16) z[(size_t)row * EMB + lane] = zn;
}

// ---------------------------------------------------------------------------
// A_pred = sigmoid(z @ z^T).  64x64 tile per block.
// ---------------------------------------------------------------------------
__global__ __launch_bounds__(256) void apred_kernel(
    const float* __restrict__ z, float* __restrict__ out)
{
    __shared__ float zr[64][20];
    __shared__ float zc[64][20];
    const int tid = threadIdx.x;
    const int r0 = blockIdx.y * 64, c0 = blockIdx.x * 64;
#pragma unroll
    for (int i = 0; i < 4; ++i) {
        int idx = tid + i * 256;
        int rr = idx >> 4, d = idx & 15;
        zr[rr][d] = z[(size_t)(r0 + rr) * EMB + d];
        zc[rr][d] = z[(size_t)(c0 + rr) * EMB + d];
    }
    __syncthreads();
    const int tx = tid & 15, ty = tid >> 4;
    float rb[4][16], cb[4][16];
#pragma unroll
    for (int i = 0; i < 4; ++i)
#pragma unroll
        for (int d = 0; d < 16; ++d) {
            rb[i][d] = zr[ty * 4 + i][d];
            cb[i][d] = zc[tx * 4 + i][d];
        }
#pragma unroll
    for (int i = 0; i < 4; ++i) {
        float4 o;
        float v[4];
#pragma unroll
        for (int j = 0; j < 4; ++j) {
            float s = 0.f;
#pragma unroll
            for (int d = 0; d < 16; ++d) s += rb[i][d] * cb[j][d];
            v[j] = 1.f / (1.f + __expf(-s));
        }
        o.x = v[0]; o.y = v[1]; o.z = v[2]; o.w = v[3];
        *reinterpret_cast<float4*>(
            &out[(size_t)(r0 + ty * 4 + i) * NN + c0 + tx * 4]) = o;
    }
}

// ---------------------------------------------------------------------------
extern "C" void kernel_launch(void* const* d_in, const int* in_sizes, int n_in,
                              void* d_out, int out_size, void* d_ws, size_t ws_size,
                              hipStream_t stream)
{
    const float* x    = (const float*)d_in[0];
    const float* adj  = (const float*)d_in[1];
    const float* Mm   = (const float*)d_in[2];
    const float* W1   = (const float*)d_in[3];
    const float* a_s1 = (const float*)d_in[4];
    const float* a_n1 = (const float*)d_in[5];
    const float* W2   = (const float*)d_in[6];
    const float* a_s2 = (const float*)d_in[7];
    const float* a_n2 = (const float*)d_in[8];

    float* out = (float*)d_out;
    float* z   = out + (size_t)NN * NN;

    char* w = (char*)d_ws;
    float* part  = (float*)w;  w += (size_t)4 * NN * HID * 4;   // 16.8 MB
    float* h1    = (float*)w;  w += (size_t)NN * HID * 4;
    float* g1    = (float*)w;  w += (size_t)NN * HID * 4;
    ushort* xf16 = (ushort*)w; w += (size_t)NN * KPAD * 2;      // 15.7 MB
    ushort* W1Th = (ushort*)w; w += (size_t)HID * KPAD * 2;     // 1 MB
    float* h2    = (float*)w;  w += (size_t)NN * EMB * 4;
    int*   nnzp  = (int*)w;    w += NN * 4;
    int*   gidx  = (int*)w;    w += (size_t)NN * MAXDEG * 4;    // 2 MB
    float* Mg    = (float*)w;  w += (size_t)NN * MAXDEG * 4;    // 2 MB
    float* fs1   = (float*)w;  w += NN * 4;
    float* fn1   = (float*)w;  w += NN * 4;
    float* fs2   = (float*)w;  w += NN * 4;
    float* fn2   = (float*)w;  w += NN * 4;

    // ---- prep ----
    xcv_kernel<<<NN * 240 / 256, 256, 0, stream>>>(x, xf16);
    conv_w1t_kernel<<<dim3(30, 4), 256, 0, stream>>>(W1, W1Th);
    extract_kernel<<<NN / 4, 256, 0, stream>>>(adj, Mm, nnzp, gidx, Mg);

    // ---- layer 1 ----
    gemm_xw1<<<dim3(32, 4, 4), 256, 0, stream>>>(xf16, W1Th, part);
    reduce_h1f_kernel<<<NN / 4, 256, 0, stream>>>(part, h1, a_s1, a_n1, fs1, fn1);
    spmm1_kernel<<<NN, 256, 0, stream>>>(nnzp, gidx, Mg, fs1, fn1, h1, g1);

    // ---- layer 2 ----
    gemm_h2_kernel<<<256, 256, 0, stream>>>(g1, W2, a_s2, a_n2, h2, fs2, fn2);
    spmm2_kernel<<<NN / 4, 256, 0, stream>>>(nnzp, gidx, Mg, fs2, fn2, h2, z);

    // ---- epilogue ----
    apred_kernel<<<dim3(64, 64), 256, 0, stream>>>(z, out);
}

// Round 6
// 109.406 us; speedup vs baseline: 1.0761x; 1.0761x over previous
//
#include <hip/hip_runtime.h>
#include <math.h>

#define NN 4096
#define NFEAT 1870
#define KPAD 2048
#define KSPLIT 8
#define KCHUNK 256
#define HID 256
#define EMB 16
#define MAXDEG 128

typedef __attribute__((ext_vector_type(8))) _Float16 f16x8;
typedef __attribute__((ext_vector_type(4))) float f32x4;

__device__ __forceinline__ ushort f2h(float f) {
    _Float16 h = (_Float16)f;
    return __builtin_bit_cast(ushort, h);
}

// ---------------------------------------------------------------------------
// Fused prep: [0,4096) xcv rows; [4096,4224) W1T convert; [4224,5248) extract.
// ---------------------------------------------------------------------------
__global__ __launch_bounds__(256) void prep_kernel(
    const float* __restrict__ x, ushort* __restrict__ xf,
    const float* __restrict__ W1, ushort* __restrict__ Wh,
    const float* __restrict__ adj, const float* __restrict__ Mmat,
    int* __restrict__ nnz, int* __restrict__ gidx, float* __restrict__ Mg)
{
    const int b = blockIdx.x;
    const int tid = threadIdx.x;
    if (b < NN) {
        // ---- x row -> f16, zero-pad to KPAD ----
        const int row = b;
        const int c0 = tid * 8;
        float v[8];
        if (c0 + 8 <= NFEAT) {
#pragma unroll
            for (int j = 0; j < 4; ++j) {
                float2 t = *(const float2*)&x[(size_t)row * NFEAT + c0 + j * 2];
                v[j * 2] = t.x; v[j * 2 + 1] = t.y;
            }
        } else {
#pragma unroll
            for (int j = 0; j < 8; ++j)
                v[j] = (c0 + j < NFEAT) ? x[(size_t)row * NFEAT + c0 + j] : 0.f;
        }
        ushort u[8];
#pragma unroll
        for (int j = 0; j < 8; ++j) u[j] = f2h(v[j]);
        *(int4*)&xf[(size_t)row * KPAD + c0] = *(int4*)u;
    } else if (b < NN + 128) {
        // ---- W1 [NFEAT][HID] -> W1T f16 [HID][KPAD], zero-padded ----
        __shared__ float t[64][65];
        const int bb = b - NN;
        const int k0 = (bb & 31) * 64, n0 = (bb >> 5) * 64;
        const int kk = tid >> 2, c4 = (tid & 3) * 16;
#pragma unroll
        for (int j = 0; j < 4; ++j) {
            int k = k0 + kk;
            float4 v = make_float4(0.f, 0.f, 0.f, 0.f);
            if (k < NFEAT) v = *(const float4*)&W1[(size_t)k * HID + n0 + c4 + j * 4];
            t[kk][c4 + j * 4 + 0] = v.x; t[kk][c4 + j * 4 + 1] = v.y;
            t[kk][c4 + j * 4 + 2] = v.z; t[kk][c4 + j * 4 + 3] = v.w;
        }
        __syncthreads();
        const int on = tid >> 2, ok4 = (tid & 3) * 16;
#pragma unroll
        for (int j = 0; j < 4; ++j) {
            ushort hh[4];
#pragma unroll
            for (int i = 0; i < 4; ++i)
                hh[i] = f2h(t[ok4 + j * 4 + i][on]);
            size_t o = (size_t)(n0 + on) * KPAD + k0 + ok4 + j * 4;
            *(ushort4*)&Wh[o] = *(ushort4*)hh;
        }
    } else {
        // ---- sparse extraction: ordered neighbor compaction, 1 wave/row ----
        __shared__ int sidx[4][MAXDEG];
        const int bb = b - NN - 128;
        const int wv = tid >> 6, lane = tid & 63;
        const int row = bb * 4 + wv;
        int base = 0;
#pragma unroll 4
        for (int t4 = 0; t4 < 16; ++t4) {
            int j0 = t4 * 256 + lane * 4;
            float4 a = *(const float4*)&adj[(size_t)row * NN + j0];
            float av[4] = {a.x, a.y, a.z, a.w};
#pragma unroll
            for (int c = 0; c < 4; ++c) {
                unsigned long long mb = __ballot(av[c] > 0.f);
                if (av[c] > 0.f) {
                    int pos = base + (int)__popcll(mb & ((1ull << lane) - 1ull));
                    if (pos < MAXDEG) sidx[wv][pos] = j0 + c;
                }
                base += (int)__popcll(mb);
            }
        }
        const int cnt = min(base, MAXDEG);
        if (lane == 0) nnz[row] = cnt;
        for (int s = lane; s < cnt; s += 64) {
            int j = sidx[wv][s];
            gidx[(size_t)row * MAXDEG + s] = j;
            Mg[(size_t)row * MAXDEG + s] = Mmat[(size_t)row * NN + j];
        }
    }
}

// ---------------------------------------------------------------------------
// h1 partials = xf16 @ W1T^T. LDS-free, barrier-free direct-global MFMA.
// Wave = 32x64 output tile; block = 4 waves covering 256 cols of 32 rows.
// Grid = 128 row-groups x 8 K-chunks = 1024 blocks. Full-unroll 8 K-steps.
// ---------------------------------------------------------------------------
__global__ __launch_bounds__(256, 4) void gemm_xw1(
    const ushort* __restrict__ Ag,   // [NN][KPAD]
    const ushort* __restrict__ Bg,   // [HID][KPAD]
    float* __restrict__ Cpart)       // [KSPLIT][NN][HID]
{
    const int tid = threadIdx.x;
    const int lane = tid & 63;
    const int cgrp = tid >> 6;          // wave = column group
    const int mgrp = blockIdx.x >> 3;
    const int z    = blockIdx.x & 7;
    const int row0 = mgrp * 32;
    const int col0 = cgrp * 64;
    const int kbeg = z * KCHUNK;

    const int fr = lane & 15, fs = lane >> 4;

    const ushort* Abase = Ag + (size_t)(row0 + fr) * KPAD + kbeg + fs * 8;
    const ushort* Bbase = Bg + (size_t)(col0 + fr) * KPAD + kbeg + fs * 8;

    f32x4 acc[2][4] = {};
#pragma unroll
    for (int sk = 0; sk < 8; ++sk) {
        f16x8 a[2], b[4];
#pragma unroll
        for (int m = 0; m < 2; ++m)
            a[m] = *(const f16x8*)&Abase[(size_t)m * 16 * KPAD + sk * 32];
#pragma unroll
        for (int n = 0; n < 4; ++n)
            b[n] = *(const f16x8*)&Bbase[(size_t)n * 16 * KPAD + sk * 32];
#pragma unroll
        for (int m = 0; m < 2; ++m)
#pragma unroll
            for (int n = 0; n < 4; ++n)
                acc[m][n] = __builtin_amdgcn_mfma_f32_16x16x32_f16(
                    a[m], b[n], acc[m][n], 0, 0, 0);
    }
    float* Cp = Cpart + (size_t)z * NN * HID;
#pragma unroll
    for (int m = 0; m < 2; ++m)
#pragma unroll
        for (int n = 0; n < 4; ++n)
#pragma unroll
            for (int r = 0; r < 4; ++r) {
                int row = row0 + m * 16 + fs * 4 + r;
                int col = col0 + n * 16 + fr;
                Cp[(size_t)row * HID + col] = acc[m][n][r];
            }
}

// ---------------------------------------------------------------------------
// h1 = sum of 8 split-K partials; fused fs1/fn1 (one wave per row).
// ---------------------------------------------------------------------------
__global__ __launch_bounds__(256) void reduce_h1f_kernel(
    const float* __restrict__ part, float* __restrict__ h1,
    const float* __restrict__ a_s, const float* __restrict__ a_n,
    float* __restrict__ fs, float* __restrict__ fn)
{
    const int tid = threadIdx.x, wv = tid >> 6, lane = tid & 63;
    const int row = blockIdx.x * 4 + wv;
    const int d0 = lane * 4;
    const size_t o = (size_t)row * HID + d0;
    float4 s = *(const float4*)&part[o];
#pragma unroll
    for (int ch = 1; ch < KSPLIT; ++ch) {
        float4 p = *(const float4*)&part[(size_t)ch * NN * HID + o];
        s.x += p.x; s.y += p.y; s.z += p.z; s.w += p.w;
    }
    *(float4*)&h1[o] = s;
    float4 as4 = *(const float4*)&a_s[d0];
    float4 an4 = *(const float4*)&a_n[d0];
    float ps = s.x * as4.x + s.y * as4.y + s.z * as4.z + s.w * as4.w;
    float pn = s.x * an4.x + s.y * an4.y + s.z * an4.z + s.w * an4.w;
#pragma unroll
    for (int off = 32; off > 0; off >>= 1) {
        ps += __shfl_down(ps, off, 64);
        pn += __shfl_down(pn, off, 64);
    }
    if (lane == 0) { fs[row] = ps; fn[row] = pn; }
}

// ---------------------------------------------------------------------------
// Layer-1 fused sparse softmax + SpMM: g1[row,:] = elu( softmax_nb @ h1 ).
// ---------------------------------------------------------------------------
__global__ __launch_bounds__(256) void spmm1_kernel(
    const int* __restrict__ nnz, const int* __restrict__ gidx,
    const float* __restrict__ Mg,
    const float* __restrict__ fs, const float* __restrict__ fn,
    const float* __restrict__ h1, float* __restrict__ g1)
{
    __shared__ float p_s[MAXDEG];
    __shared__ int j_s[MAXDEG];
    __shared__ float wred[4], wsum[4];
    const int row = blockIdx.x;
    const int tid = threadIdx.x;
    const int lane = tid & 63, wv = tid >> 6;
    const int cnt = nnz[row];
    const float fsi = fs[row];

    float lmax = -3.0e38f;
    for (int s = tid; s < cnt; s += 256) {
        int j = gidx[(size_t)row * MAXDEG + s];
        j_s[s] = j;
        float e = (fsi + fn[j]) * Mg[(size_t)row * MAXDEG + s];
        e = (e > 0.f) ? e : 0.2f * e;
        p_s[s] = e;
        lmax = fmaxf(lmax, e);
    }
#pragma unroll
    for (int off = 32; off > 0; off >>= 1)
        lmax = fmaxf(lmax, __shfl_down(lmax, off, 64));
    if (lane == 0) wred[wv] = lmax;
    __syncthreads();
    const float m = fmaxf(fmaxf(wred[0], wred[1]), fmaxf(wred[2], wred[3]));

    float lsum = 0.f;
    for (int s = tid; s < cnt; s += 256) {
        float p = __expf(p_s[s] - m);
        p_s[s] = p;
        lsum += p;
    }
#pragma unroll
    for (int off = 32; off > 0; off >>= 1)
        lsum += __shfl_down(lsum, off, 64);
    if (lane == 0) wsum[wv] = lsum;
    __syncthreads();
    const float inv = 1.f / (wsum[0] + wsum[1] + wsum[2] + wsum[3]);

    float acc = 0.f;
#pragma unroll 4
    for (int s = 0; s < cnt; ++s)
        acc += p_s[s] * h1[(size_t)j_s[s] * HID + tid];
    float v = acc * inv;
    v = (v > 0.f) ? v : (__expf(v) - 1.f);
    g1[(size_t)row * HID + tid] = v;
}

// ---------------------------------------------------------------------------
// h2 = g1 @ W2 with fused fs2/fn2 epilogue.
// ---------------------------------------------------------------------------
__global__ __launch_bounds__(256) void gemm_h2_kernel(
    const float* __restrict__ g1, const float* __restrict__ W2,
    const float* __restrict__ a_s2, const float* __restrict__ a_n2,
    float* __restrict__ h2, float* __restrict__ fs2, float* __restrict__ fn2)
{
    __shared__ float Ws[256][16];
    __shared__ float Gs[16][257];
    const int tid = threadIdx.x;
    const int row0 = blockIdx.x * 16;
#pragma unroll
    for (int i = 0; i < 16; ++i) {
        int idx = tid + i * 256;
        Ws[idx >> 4][idx & 15] = W2[idx];
    }
#pragma unroll
    for (int i = 0; i < 16; ++i) {
        int idx = tid + i * 256;
        Gs[idx >> 8][idx & 255] = g1[(size_t)(row0 + (idx >> 8)) * HID + (idx & 255)];
    }
    __syncthreads();
    const int r = tid >> 4, c = tid & 15;
    float acc = 0.f;
#pragma unroll 8
    for (int k = 0; k < 256; ++k)
        acc += Gs[r][k] * Ws[k][c];
    h2[(size_t)(row0 + r) * EMB + c] = acc;

    float ps = acc * a_s2[c];
    float pn = acc * a_n2[c];
#pragma unroll
    for (int off = 1; off < 16; off <<= 1) {
        ps += __shfl_xor(ps, off, 64);
        pn += __shfl_xor(pn, off, 64);
    }
    if (c == 0) { fs2[row0 + r] = ps; fn2[row0 + r] = pn; }
}

// ---------------------------------------------------------------------------
// Layer-2 fused sparse softmax + PV + ELU + L2-normalize -> z. 1 wave/row.
// ---------------------------------------------------------------------------
__global__ __launch_bounds__(256) void spmm2_kernel(
    const int* __restrict__ nnz, const int* __restrict__ gidx,
    const float* __restrict__ Mg,
    const float* __restrict__ fs, const float* __restrict__ fn,
    const float* __restrict__ h2, float* __restrict__ z)
{
    __shared__ float p_s[4][MAXDEG];
    __shared__ int j_s[4][MAXDEG];
    const int tid = threadIdx.x;
    const int wv = tid >> 6, lane = tid & 63;
    const int row = blockIdx.x * 4 + wv;
    const int cnt = nnz[row];
    const float fsi = fs[row];

    float lmax = -3.0e38f;
    for (int s = lane; s < cnt; s += 64) {
        int j = gidx[(size_t)row * MAXDEG + s];
        j_s[wv][s] = j;
        float e = (fsi + fn[j]) * Mg[(size_t)row * MAXDEG + s];
        e = (e > 0.f) ? e : 0.2f * e;
        p_s[wv][s] = e;
        lmax = fmaxf(lmax, e);
    }
#pragma unroll
    for (int off = 1; off < 64; off <<= 1)
        lmax = fmaxf(lmax, __shfl_xor(lmax, off, 64));

    float lsum = 0.f;
    for (int s = lane; s < cnt; s += 64) {
        float p = __expf(p_s[wv][s] - lmax);
        p_s[wv][s] = p;
        lsum += p;
    }
#pragma unroll
    for (int off = 1; off < 64; off <<= 1)
        lsum += __shfl_xor(lsum, off, 64);
    const float inv = 1.f / lsum;

    const int s0 = lane >> 4, d = lane & 15;
    float acc = 0.f;
    for (int s = s0; s < cnt; s += 4)
        acc += p_s[wv][s] * h2[(size_t)j_s[wv][s] * EMB + d];
    acc += __shfl_xor(acc, 16, 64);
    acc += __shfl_xor(acc, 32, 64);

    float v = acc * inv;
    v = (v > 0.f) ? v : (__expf(v) - 1.f);
    float ss = v * v;
#pragma unroll
    for (int off = 1; off < 16; off <<= 1)
        ss += __shfl_xor(ss, off, 64);
    float zn = v / fmaxf(sqrtf(ss), 1e-12f);
    if (lane < 16) z[(size_t)row * EMB + lane] = zn;
}

// ---------------------------------------------------------------------------
// A_pred = sigmoid(z @ z^T).  64x64 tile per block.
// ---------------------------------------------------------------------------
__global__ __launch_bounds__(256) void apred_kernel(
    const float* __restrict__ z, float* __restrict__ out)
{
    __shared__ float zr[64][20];
    __shared__ float zc[64][20];
    const int tid = threadIdx.x;
    const int r0 = blockIdx.y * 64, c0 = blockIdx.x * 64;
#pragma unroll
    for (int i = 0; i < 4; ++i) {
        int idx = tid + i * 256;
        int rr = idx >> 4, d = idx & 15;
        zr[rr][d] = z[(size_t)(r0 + rr) * EMB + d];
        zc[rr][d] = z[(size_t)(c0 + rr) * EMB + d];
    }
    __syncthreads();
    const int tx = tid & 15, ty = tid >> 4;
    float rb[4][16], cb[4][16];
#pragma unroll
    for (int i = 0; i < 4; ++i)
#pragma unroll
        for (int d = 0; d < 16; ++d) {
            rb[i][d] = zr[ty * 4 + i][d];
            cb[i][d] = zc[tx * 4 + i][d];
        }
#pragma unroll
    for (int i = 0; i < 4; ++i) {
        float4 o;
        float v[4];
#pragma unroll
        for (int j = 0; j < 4; ++j) {
            float s = 0.f;
#pragma unroll
            for (int d = 0; d < 16; ++d) s += rb[i][d] * cb[j][d];
            v[j] = 1.f / (1.f + __expf(-s));
        }
        o.x = v[0]; o.y = v[1]; o.z = v[2]; o.w = v[3];
        *reinterpret_cast<float4*>(
            &out[(size_t)(r0 + ty * 4 + i) * NN + c0 + tx * 4]) = o;
    }
}

// ---------------------------------------------------------------------------
extern "C" void kernel_launch(void* const* d_in, const int* in_sizes, int n_in,
                              void* d_out, int out_size, void* d_ws, size_t ws_size,
                              hipStream_t stream)
{
    const float* x    = (const float*)d_in[0];
    const float* adj  = (const float*)d_in[1];
    const float* Mm   = (const float*)d_in[2];
    const float* W1   = (const float*)d_in[3];
    const float* a_s1 = (const float*)d_in[4];
    const float* a_n1 = (const float*)d_in[5];
    const float* W2   = (const float*)d_in[6];
    const float* a_s2 = (const float*)d_in[7];
    const float* a_n2 = (const float*)d_in[8];

    float* out = (float*)d_out;
    float* z   = out + (size_t)NN * NN;
    // split-K partials live in the (dead until apred) A_pred region: 33.5 MB
    float* part = out;

    char* w = (char*)d_ws;
    float* h1    = (float*)w;  w += (size_t)NN * HID * 4;       // 4 MB
    float* g1    = (float*)w;  w += (size_t)NN * HID * 4;       // 4 MB
    ushort* xf16 = (ushort*)w; w += (size_t)NN * KPAD * 2;      // 16.8 MB
    ushort* W1Th = (ushort*)w; w += (size_t)HID * KPAD * 2;     // 1 MB
    float* h2    = (float*)w;  w += (size_t)NN * EMB * 4;
    int*   nnzp  = (int*)w;    w += NN * 4;
    int*   gidx  = (int*)w;    w += (size_t)NN * MAXDEG * 4;    // 2 MB
    float* Mg    = (float*)w;  w += (size_t)NN * MAXDEG * 4;    // 2 MB
    float* fs1   = (float*)w;  w += NN * 4;
    float* fn1   = (float*)w;  w += NN * 4;
    float* fs2   = (float*)w;  w += NN * 4;
    float* fn2   = (float*)w;  w += NN * 4;

    // ---- fused prep: x->f16 | W1T->f16 | sparsity extraction ----
    prep_kernel<<<NN + 128 + NN / 4, 256, 0, stream>>>(
        x, xf16, W1, W1Th, adj, Mm, nnzp, gidx, Mg);

    // ---- layer 1 ----
    gemm_xw1<<<(NN / 32) * KSPLIT, 256, 0, stream>>>(xf16, W1Th, part);
    reduce_h1f_kernel<<<NN / 4, 256, 0, stream>>>(part, h1, a_s1, a_n1, fs1, fn1);
    spmm1_kernel<<<NN, 256, 0, stream>>>(nnzp, gidx, Mg, fs1, fn1, h1, g1);

    // ---- layer 2 ----
    gemm_h2_kernel<<<256, 256, 0, stream>>>(g1, W2, a_s2, a_n2, h2, fs2, fn2);
    spmm2_kernel<<<NN / 4, 256, 0, stream>>>(nnzp, gidx, Mg, fs2, fn2, h2, z);

    // ---- epilogue ----
    apred_kernel<<<dim3(64, 64), 256, 0, stream>>>(z, out);
}